// Round 7
// baseline (641.606 us; speedup 1.0000x reference)
//
#include <hip/hip_runtime.h>

typedef __attribute__((ext_vector_type(4))) float f32x4_t;
typedef __attribute__((ext_vector_type(8))) short bf16x8_t;

#define NROWS 16384
#define NCODES 4096
#define DIM 512
#define LSTR 65
#define DELTA 0.005f     // > worst-case |f64 referee - hi-only bf16 pass1| = 0.0040
#define MAXC 16          // candidate cap per row

// ---------------- workspace byte offsets (~39.2 MB; harness provides >=45.6 MB, proven round 4) ----------------
#define WS_A      0u          // 128 tb x 16 st x 8KB  -> 16777216
#define WS_B      16777216u   //  32 ct x 16 st x 8KB  -> 20971520
#define WS_TOP4   20971520u   // 16384 x 32 grp x 4 slot x float2 -> 37748736
#define WS_COUNTS 37748736u   // 4096 u32 -> 37765120
#define WS_FLAGS  37765120u   // [0]=mask-layout [1]=cand_cnt [2]=full_cnt -> +64
#define WS_IDX    37765184u   // 16384 i32 -> 37830720
#define WS_CANDS  37830720u   // 16384 x 20 i32 -> 39141440
#define WS_FULL   39141440u   // 16384 i32 -> 39206976
#define WS_CPART  39206976u   // 4096 f64 -> 39239744

// output element offsets (flat f32)
#define OUT_ZQ      0
#define OUT_ZQST    8388608
#define OUT_IDX     16777216
#define OUT_VQ      16793600
#define OUT_COMMIT  16793601
#define OUT_PERP    16793602

__device__ __forceinline__ unsigned short f2bf(float x) {
  unsigned u = __builtin_bit_cast(unsigned, x);
  unsigned r = (u + 0x7FFFu + ((u >> 16) & 1u)) >> 16;  // RNE
  return (unsigned short)r;
}
__device__ __forceinline__ unsigned hz(unsigned x) {
  return (x - 0x01010101u) & ~x & 0x80808080u;  // any zero byte
}
// line-paired XOR LDS/chunk layout for BK=32 rows (64B): r in [0,128), u in [0,4)
__device__ __forceinline__ unsigned swz_off(int r, int u) {
  return (unsigned)((r >> 1) * 128 + ((((r & 1) * 4 + u) ^ ((r >> 1) & 7)) << 4));
}

// ---------------- prep: norms + bf16-hi convert into swizzled 8KB chunks + zero counts/flags ----------------
__global__ void prep_kernel(const float* __restrict__ z, const float* __restrict__ cb,
                            unsigned char* __restrict__ Aws, unsigned char* __restrict__ Bws,
                            unsigned* __restrict__ counts) {
  if (blockIdx.x < 17) {
    int zi = blockIdx.x * 256 + threadIdx.x;
    if (zi < 4100) counts[zi] = 0;  // counts[4096] + flags[4] contiguous
  }
  const int wv = threadIdx.x >> 6, lane = threadIdx.x & 63;
  const int row = blockIdx.x * 4 + wv;
  if (row >= NROWS + NCODES) return;
  const bool isA = row < NROWS;
  const int lrow = isA ? row : row - NROWS;
  const float* src = (isA ? z : cb) + (size_t)lrow * DIM;
  f32x4_t a = *(const f32x4_t*)(src + lane * 8);
  f32x4_t b = *(const f32x4_t*)(src + lane * 8 + 4);
  double s = 0.0;
#pragma unroll
  for (int e = 0; e < 4; ++e) s += (double)a[e] * a[e] + (double)b[e] * b[e];
#pragma unroll
  for (int off = 1; off < 64; off <<= 1) s += __shfl_xor(s, off);
  const float inv = (float)(1.0 / fmax(sqrt(s), 1e-8));
  union { unsigned short u[8]; uint4 v; } H;
#pragma unroll
  for (int e = 0; e < 4; ++e) {
    H.u[e] = f2bf(a[e] * inv);
    H.u[4 + e] = f2bf(b[e] * inv);
  }
  const int tb = lrow >> 7, rr = lrow & 127;
  const int st = lane >> 2, cu = lane & 3;  // stage = 32 cols, unit = 8 cols
  unsigned char* chunk = (isA ? Aws : Bws) + ((size_t)tb * 16 + st) * 8192;
  *(uint4*)(chunk + swz_off(rr, cu)) = H.v;
}

// ---------------- pass-1 GEMM: m97-style single-buffer, plain __syncthreads, top-4 per (row,ctile) ----------------
__global__ __launch_bounds__(256, 4) void gemm_p1_kernel(
    const unsigned char* __restrict__ Aws, const unsigned char* __restrict__ Bws,
    float2* __restrict__ top4) {
  __align__(16) __shared__ unsigned char smem[33280];  // staging 16KB (A 8K|B 8K) UNION slog 128x65 f32
  float* slog = (float*)smem;

  const int tid = threadIdx.x;
  const int bid = blockIdx.x;
  const int xcd = bid & 7, q = bid >> 3;
  const int rb = xcd * 16 + (q >> 3), cg = q & 7;  // XCD-aware: 8 cg-blocks of one rb share an XCD L2
  const int wave = tid >> 6, lane = tid & 63;
  const int wr = wave >> 1, wc = wave & 1;
  const int kg = lane >> 4, lr = lane & 15;

  const unsigned char* Ach = Aws + (size_t)rb * 16 * 8192;

  for (int ct = 0; ct < 4; ++ct) {
    const int ctile = cg * 4 + ct;
    const int code0 = ctile * 128;
    const unsigned char* Bch = Bws + (size_t)ctile * 16 * 8192;

    f32x4_t acc[4][4];
#pragma unroll
    for (int m = 0; m < 4; ++m)
#pragma unroll
      for (int n = 0; n < 4; ++n) acc[m][n] = (f32x4_t){0.f, 0.f, 0.f, 0.f};

    for (int st = 0; st < 16; ++st) {
      const unsigned char* Asrc = Ach + (size_t)st * 8192;
      const unsigned char* Bsrc = Bch + (size_t)st * 8192;
#pragma unroll
      for (int i = 0; i < 4; ++i) {
        const int j = wave * 4 + i;  // 16 x 1KB units: A 0-7, B 8-15
        const unsigned char* sp = (j < 8) ? (Asrc + (size_t)j * 1024 + lane * 16)
                                          : (Bsrc + (size_t)(j - 8) * 1024 + lane * 16);
        __builtin_amdgcn_global_load_lds(
            (const __attribute__((address_space(1))) void*)sp,
            (__attribute__((address_space(3))) void*)(smem + j * 1024), 16, 0, 0);
      }
      __syncthreads();  // compiler drains vmcnt before barrier (m97 pattern)

      bf16x8_t ah[4], bh[4];
#pragma unroll
      for (int m = 0; m < 4; ++m) {
        const int r = wr * 64 + m * 16 + lr;
        ah[m] = *(const bf16x8_t*)(smem + swz_off(r, kg));
      }
#pragma unroll
      for (int n = 0; n < 4; ++n) {
        const int r = wc * 64 + n * 16 + lr;
        bh[n] = *(const bf16x8_t*)(smem + 8192 + swz_off(r, kg));
      }
#pragma unroll
      for (int m = 0; m < 4; ++m)
#pragma unroll
        for (int n = 0; n < 4; ++n)
          acc[m][n] = __builtin_amdgcn_mfma_f32_16x16x32_bf16(ah[m], bh[n], acc[m][n], 0, 0, 0);
      __syncthreads();  // reads done before next stage overwrites
    }

    // epilogue: 64-col halves through LDS, per-row top-4 for THIS ctile (regs live only here)
    float v4[4]; int id4[4];
#pragma unroll
    for (int s = 0; s < 4; ++s) { v4[s] = -3e38f; id4[s] = 0; }
#pragma unroll
    for (int ph = 0; ph < 2; ++ph) {
      if (wc == ph) {
#pragma unroll
        for (int m = 0; m < 4; ++m)
#pragma unroll
          for (int n = 0; n < 4; ++n)
#pragma unroll
            for (int j = 0; j < 4; ++j)
              slog[(wr * 64 + m * 16 + kg * 4 + j) * LSTR + n * 16 + lr] = acc[m][n][j];
      }
      __syncthreads();
      if (tid < 128) {
        const int gbase = code0 + ph * 64;
        for (int c = 0; c < 64; ++c) {
          float v = slog[tid * LSTR + c];
          if (v > v4[3]) {
            v4[3] = v; id4[3] = gbase + c;
#pragma unroll
            for (int s = 3; s > 0; --s)
              if (v4[s] > v4[s - 1]) {
                float tv = v4[s]; v4[s] = v4[s - 1]; v4[s - 1] = tv;
                int ti = id4[s]; id4[s] = id4[s - 1]; id4[s - 1] = ti;
              }
          }
        }
      }
      __syncthreads();
    }
    if (tid < 128) {
      float2* p = top4 + ((size_t)(rb * 128 + tid) * 32 + ctile) * 4;
#pragma unroll
      for (int s = 0; s < 4; ++s)
        p[s] = make_float2(v4[s], __builtin_bit_cast(float, id4[s]));
    }
  }
}

// ---------------- resolve: mask probe + merge 32x top-4, classify rows ----------------
__global__ void resolve_kernel(const uint4* __restrict__ mk, const float2* __restrict__ top4,
                               int* __restrict__ idxf, int* __restrict__ cands,
                               int* __restrict__ full, unsigned* __restrict__ flags) {
  if (blockIdx.x == 0) {
    unsigned f = 0;
    for (int i = threadIdx.x; i < 1024; i += 256) {
      uint4 v = mk[i];
      f |= hz(v.x) | hz(v.y) | hz(v.z) | hz(v.w);
    }
    if (f) atomicOr(&flags[0], 1u);  // zero byte found -> int32 mask layout
  }
  const int row = blockIdx.x * 256 + threadIdx.x;
  if (row >= NROWS) return;
  const float2* e = top4 + (size_t)row * 128;  // 32 groups x 4 slots
  float V1 = -3e38f; int I1 = 0;
  for (int j = 0; j < 128; ++j) {
    float v = e[j].x;
    if (v > V1) { V1 = v; I1 = __builtin_bit_cast(int, e[j].y); }
  }
  const float T = V1 - 2.0f * DELTA;
  bool fullscan = false;
#pragma unroll
  for (int g = 0; g < 32; ++g)
    if (e[g * 4 + 3].x >= T) fullscan = true;  // group top-4 may have truncated candidates
  int cnt = 0; int cid[MAXC];
  for (int j = 0; j < 128; ++j) {
    if (e[j].x >= T) { if (cnt < MAXC) cid[cnt] = __builtin_bit_cast(int, e[j].y); ++cnt; }
  }
  if (cnt > MAXC) fullscan = true;
  idxf[row] = I1;  // provably correct when cnt==1
  if (fullscan) {
    unsigned s = atomicAdd(&flags[2], 1u);
    if (s < NROWS) full[s] = row;
  } else if (cnt >= 2) {
    unsigned s = atomicAdd(&flags[1], 1u);
    int* o = cands + (size_t)s * 20;
    o[0] = row; o[1] = cnt;
#pragma unroll
    for (int c2 = 0; c2 < MAXC; ++c2) o[2 + c2] = (c2 < cnt) ? cid[c2] : 0;
  }
}

// ---------------- f64 candidate rescore: one wave per row ----------------
__global__ void rescore_cand_kernel(const float* __restrict__ z, const float* __restrict__ cb,
                                    const int* __restrict__ cands, const unsigned* __restrict__ flags,
                                    int* __restrict__ idxf) {
  const int lane = threadIdx.x & 63;
  const int gw = (blockIdx.x * 256 + threadIdx.x) >> 6;
  const unsigned n = flags[1];
  for (unsigned it = gw; it < n; it += 512) {
    const int* en = cands + (size_t)it * 20;
    const int row = en[0], cnt = en[1];
    const float* zr = z + (size_t)row * DIM + lane * 8;
    double zv[8];
#pragma unroll
    for (int j = 0; j < 8; ++j) zv[j] = (double)zr[j];
    double bs = -1e300; int bi = 1 << 30;
    for (int c = 0; c < cnt; ++c) {
      const int k = en[2 + c];
      const float* ck = cb + (size_t)k * DIM + lane * 8;
      double da = 0, nb = 0;
#pragma unroll
      for (int j = 0; j < 8; ++j) { double cv = ck[j]; da += zv[j] * cv; nb += cv * cv; }
#pragma unroll
      for (int off = 1; off < 64; off <<= 1) {
        da += __shfl_xor(da, off); nb += __shfl_xor(nb, off);
      }
      double sc = da / sqrt(nb);  // z-norm omitted: row-constant scale, argmax-invariant
      if (sc > bs || (sc == bs && k < bi)) { bs = sc; bi = k; }
    }
    if (lane == 0) idxf[row] = bi;
  }
}

// ---------------- f64 full-row referee: one BLOCK per row, ILP-4 per thread ----------------
__global__ void rescore_full_kernel(const float* __restrict__ z, const float* __restrict__ cb,
                                    const int* __restrict__ full, const unsigned* __restrict__ flags,
                                    int* __restrict__ idxf) {
  __shared__ float zrow[DIM];
  __shared__ double rv[256];
  __shared__ int ri[256];
  const int t = threadIdx.x;
  const unsigned n = flags[2];
  for (unsigned it = blockIdx.x; it < n; it += gridDim.x) {
    const int row = full[it];
    __syncthreads();
    for (int j = t; j < DIM; j += 256) zrow[j] = z[(size_t)row * DIM + j];
    __syncthreads();
    double best = -1e300; int bi = 1 << 30;
    for (int b = 0; b < 4; ++b) {
      const int k0 = t + b * 1024;
      const float* c0 = cb + (size_t)(k0)       * DIM;
      const float* c1 = cb + (size_t)(k0 + 256) * DIM;
      const float* c2 = cb + (size_t)(k0 + 512) * DIM;
      const float* c3 = cb + (size_t)(k0 + 768) * DIM;
      double d0 = 0, d1 = 0, d2 = 0, d3 = 0, n0 = 0, n1 = 0, n2 = 0, n3 = 0;
      for (int j = 0; j < DIM; j += 4) {
        f32x4_t zq = *(const f32x4_t*)(zrow + j);
        f32x4_t a0 = *(const f32x4_t*)(c0 + j);
        f32x4_t a1 = *(const f32x4_t*)(c1 + j);
        f32x4_t a2 = *(const f32x4_t*)(c2 + j);
        f32x4_t a3 = *(const f32x4_t*)(c3 + j);
#pragma unroll
        for (int e = 0; e < 4; ++e) {
          const double zd = (double)zq[e];
          const double v0 = (double)a0[e], v1 = (double)a1[e];
          const double v2 = (double)a2[e], v3 = (double)a3[e];
          d0 += zd * v0; n0 += v0 * v0;
          d1 += zd * v1; n1 += v1 * v1;
          d2 += zd * v2; n2 += v2 * v2;
          d3 += zd * v3; n3 += v3 * v3;
        }
      }
      const double s0 = d0 / sqrt(n0), s1 = d1 / sqrt(n1);
      const double s2 = d2 / sqrt(n2), s3 = d3 / sqrt(n3);
      if (s0 > best || (s0 == best && k0       < bi)) { best = s0; bi = k0; }
      if (s1 > best || (s1 == best && k0 + 256 < bi)) { best = s1; bi = k0 + 256; }
      if (s2 > best || (s2 == best && k0 + 512 < bi)) { best = s2; bi = k0 + 512; }
      if (s3 > best || (s3 == best && k0 + 768 < bi)) { best = s3; bi = k0 + 768; }
    }
    rv[t] = best; ri[t] = bi; __syncthreads();
    for (int off = 128; off; off >>= 1) {
      if (t < off) {
        if (rv[t + off] > rv[t] || (rv[t + off] == rv[t] && ri[t + off] < ri[t])) {
          rv[t] = rv[t + off]; ri[t] = ri[t + off];
        }
      }
      __syncthreads();
    }
    if (t == 0) idxf[row] = ri[0];
  }
}

// ---------------- gather + straight-through + partial losses ----------------
__global__ void outputs_kernel(const float* __restrict__ z, const float* __restrict__ cb,
                               const unsigned char* __restrict__ mask8, const int* __restrict__ mask32,
                               const unsigned* __restrict__ flags, const int* __restrict__ idxf,
                               float* __restrict__ out, unsigned* __restrict__ counts,
                               double* __restrict__ cpart) {
  __shared__ double wsum[4];
  const int wv = threadIdx.x >> 6, lane = threadIdx.x & 63;
  const int row = blockIdx.x * 4 + wv;
  int idx = idxf[row];
  idx = (idx < 0) ? 0 : ((idx > NCODES - 1) ? NCODES - 1 : idx);  // defensive clamp
  const int mi = flags[0] ? (mask32[row] != 0) : (mask8[row] != 0);
  const float mf = mi ? 1.0f : 0.0f;
  const float* zr = z + (size_t)row * DIM;
  const float* cr = cb + (size_t)idx * DIM;
  double cs = 0.0;
#pragma unroll
  for (int h = 0; h < 2; ++h) {
    const int j = h * 256 + lane * 4;
    f32x4_t c  = *(const f32x4_t*)(cr + j);
    f32x4_t ze = *(const f32x4_t*)(zr + j);
    f32x4_t zq, zs;
#pragma unroll
    for (int e = 0; e < 4; ++e) {
      float qv = c[e] * mf;
      float d = qv - ze[e];
      zq[e] = qv;
      zs[e] = ze[e] + d;
      cs += (double)(d * d) * mf;
    }
    *(f32x4_t*)(out + OUT_ZQ   + (size_t)row * DIM + j) = zq;
    *(f32x4_t*)(out + OUT_ZQST + (size_t)row * DIM + j) = zs;
  }
#pragma unroll
  for (int off = 32; off; off >>= 1) cs += __shfl_down(cs, off);
  if (lane == 0) {
    wsum[wv] = cs;
    out[OUT_IDX + row] = (float)idx;
    if (mi) atomicAdd(&counts[idx], 1u);
  }
  __syncthreads();
  if (threadIdx.x == 0) cpart[blockIdx.x] = wsum[0] + wsum[1] + wsum[2] + wsum[3];
}

// ---------------- scalars ----------------
__global__ void finalize_kernel(const double* __restrict__ cpart, const unsigned* __restrict__ counts,
                                float* __restrict__ out) {
  __shared__ double sd[256];
  const int t = threadIdx.x;
  double s = 0;
  for (int i = t; i < 4096; i += 256) s += cpart[i];
  sd[t] = s; __syncthreads();
  for (int off = 128; off; off >>= 1) { if (t < off) sd[t] += sd[t + off]; __syncthreads(); }
  const double commit_sum = sd[0];
  __syncthreads();
  double c = 0;
  for (int i = t; i < 4096; i += 256) c += (double)counts[i];
  sd[t] = c; __syncthreads();
  for (int off = 128; off; off >>= 1) { if (t < off) sd[t] += sd[t + off]; __syncthreads(); }
  const double totc = sd[0];
  __syncthreads();
  const double denom = totc + 1e-5;
  double ent = 0;
  for (int i = t; i < 4096; i += 256) {
    double p = (double)counts[i] / denom;
    ent -= p * log(p + 1e-5);
  }
  sd[t] = ent; __syncthreads();
  for (int off = 128; off; off >>= 1) { if (t < off) sd[t] += sd[t + off]; __syncthreads(); }
  if (t == 0) {
    const double valid = fmax(totc, 1.0);
    const double commitment = commit_sum / valid;
    out[OUT_VQ]     = (float)(0.25 * commitment);
    out[OUT_COMMIT] = (float)commitment;
    out[OUT_PERP]   = (float)exp(sd[0]);
  }
}

extern "C" void kernel_launch(void* const* d_in, const int* in_sizes, int n_in,
                              void* d_out, int out_size, void* d_ws, size_t ws_size,
                              hipStream_t stream) {
  const float* z  = (const float*)d_in[0];
  const void*  mk = d_in[1];
  const float* cb = (const float*)d_in[2];
  float* out = (float*)d_out;
  char* ws = (char*)d_ws;

  unsigned char* Aws    = (unsigned char*)(ws + WS_A);
  unsigned char* Bws    = (unsigned char*)(ws + WS_B);
  float2*        top4   = (float2*)(ws + WS_TOP4);
  unsigned*      counts = (unsigned*)(ws + WS_COUNTS);
  unsigned*      flags  = (unsigned*)(ws + WS_FLAGS);
  int*           idxf   = (int*)(ws + WS_IDX);
  int*           cands  = (int*)(ws + WS_CANDS);
  int*           full   = (int*)(ws + WS_FULL);
  double*        cpart  = (double*)(ws + WS_CPART);

  prep_kernel<<<(NROWS + NCODES) / 4, 256, 0, stream>>>(z, cb, Aws, Bws, counts);
  gemm_p1_kernel<<<1024, 256, 0, stream>>>(Aws, Bws, top4);
  resolve_kernel<<<NROWS / 256, 256, 0, stream>>>((const uint4*)mk, top4, idxf, cands, full, flags);
  rescore_cand_kernel<<<128, 256, 0, stream>>>(z, cb, cands, flags, idxf);
  rescore_full_kernel<<<256, 256, 0, stream>>>(z, cb, full, flags, idxf);
  outputs_kernel<<<NROWS / 4, 256, 0, stream>>>(z, cb, (const unsigned char*)mk, (const int*)mk,
                                                flags, idxf, out, counts, cpart);
  finalize_kernel<<<1, 256, 0, stream>>>(cpart, counts, out);
}

// Round 8
// 392.735 us; speedup vs baseline: 1.6337x; 1.6337x over previous
//
#include <hip/hip_runtime.h>

typedef __attribute__((ext_vector_type(4))) float f32x4_t;
typedef __attribute__((ext_vector_type(8))) short bf16x8_t;

#define NROWS 16384
#define NCODES 4096
#define DIM 512
#define LSTR 65
#define DELTA 0.005f     // > worst-case |f64 referee - hi-only bf16 pass1| = 0.0040
#define MAXC 16          // candidate cap per row
#define FULL_CAP 4096u   // max full-scan rows (measured fcnt ~1-2; 1000x margin)

// ---------------- workspace byte offsets (~41.3 MB; harness provides >=45.6 MB, proven round 4) ----------------
#define WS_A      0u          // 128 tb x 16 st x 8KB  -> 16777216
#define WS_B      16777216u   //  32 ct x 16 st x 8KB  -> 20971520
#define WS_TOP4   20971520u   // 16384 x 32 grp x 4 slot x float2 -> 37748736
#define WS_COUNTS 37748736u   // 4096 u32 -> 37765120
#define WS_FLAGS  37765120u   // [0]=mask-layout [1]=cand_cnt [2]=full_cnt -> +64
#define WS_IDX    37765184u   // 16384 i32 -> 37830720
#define WS_CANDS  37830720u   // 16384 x 20 i32 -> 39141440
#define WS_FULL   39141440u   // 16384 i32 -> 39206976
#define WS_CPART  39206976u   // 4096 f64 -> 39239744
#define WS_FPART  39239744u   // 4096 x 32 x double2 -> 41336896

// output element offsets (flat f32)
#define OUT_ZQ      0
#define OUT_ZQST    8388608
#define OUT_IDX     16777216
#define OUT_VQ      16793600
#define OUT_COMMIT  16793601
#define OUT_PERP    16793602

__device__ __forceinline__ unsigned short f2bf(float x) {
  unsigned u = __builtin_bit_cast(unsigned, x);
  unsigned r = (u + 0x7FFFu + ((u >> 16) & 1u)) >> 16;  // RNE
  return (unsigned short)r;
}
__device__ __forceinline__ unsigned hz(unsigned x) {
  return (x - 0x01010101u) & ~x & 0x80808080u;  // any zero byte
}
// line-paired XOR LDS/chunk layout for BK=32 rows (64B): r in [0,128), u in [0,4)
__device__ __forceinline__ unsigned swz_off(int r, int u) {
  return (unsigned)((r >> 1) * 128 + ((((r & 1) * 4 + u) ^ ((r >> 1) & 7)) << 4));
}

// ---------------- prep: norms + bf16-hi convert into swizzled 8KB chunks + zero counts/flags ----------------
__global__ void prep_kernel(const float* __restrict__ z, const float* __restrict__ cb,
                            unsigned char* __restrict__ Aws, unsigned char* __restrict__ Bws,
                            unsigned* __restrict__ counts) {
  if (blockIdx.x < 17) {
    int zi = blockIdx.x * 256 + threadIdx.x;
    if (zi < 4100) counts[zi] = 0;  // counts[4096] + flags[4] contiguous
  }
  const int wv = threadIdx.x >> 6, lane = threadIdx.x & 63;
  const int row = blockIdx.x * 4 + wv;
  if (row >= NROWS + NCODES) return;
  const bool isA = row < NROWS;
  const int lrow = isA ? row : row - NROWS;
  const float* src = (isA ? z : cb) + (size_t)lrow * DIM;
  f32x4_t a = *(const f32x4_t*)(src + lane * 8);
  f32x4_t b = *(const f32x4_t*)(src + lane * 8 + 4);
  double s = 0.0;
#pragma unroll
  for (int e = 0; e < 4; ++e) s += (double)a[e] * a[e] + (double)b[e] * b[e];
#pragma unroll
  for (int off = 1; off < 64; off <<= 1) s += __shfl_xor(s, off);
  const float inv = (float)(1.0 / fmax(sqrt(s), 1e-8));
  union { unsigned short u[8]; uint4 v; } H;
#pragma unroll
  for (int e = 0; e < 4; ++e) {
    H.u[e] = f2bf(a[e] * inv);
    H.u[4 + e] = f2bf(b[e] * inv);
  }
  const int tb = lrow >> 7, rr = lrow & 127;
  const int st = lane >> 2, cu = lane & 3;  // stage = 32 cols, unit = 8 cols
  unsigned char* chunk = (isA ? Aws : Bws) + ((size_t)tb * 16 + st) * 8192;
  *(uint4*)(chunk + swz_off(rr, cu)) = H.v;
}

// ---------------- pass-1 GEMM: m97-style single-buffer, plain __syncthreads, top-4 per (row,ctile) ----------------
__global__ __launch_bounds__(256, 4) void gemm_p1_kernel(
    const unsigned char* __restrict__ Aws, const unsigned char* __restrict__ Bws,
    float2* __restrict__ top4) {
  __align__(16) __shared__ unsigned char smem[33280];  // staging 16KB (A 8K|B 8K) UNION slog 128x65 f32
  float* slog = (float*)smem;

  const int tid = threadIdx.x;
  const int bid = blockIdx.x;
  const int xcd = bid & 7, q = bid >> 3;
  const int rb = xcd * 16 + (q >> 3), cg = q & 7;  // XCD-aware: 8 cg-blocks of one rb share an XCD L2
  const int wave = tid >> 6, lane = tid & 63;
  const int wr = wave >> 1, wc = wave & 1;
  const int kg = lane >> 4, lr = lane & 15;

  const unsigned char* Ach = Aws + (size_t)rb * 16 * 8192;

  for (int ct = 0; ct < 4; ++ct) {
    const int ctile = cg * 4 + ct;
    const int code0 = ctile * 128;
    const unsigned char* Bch = Bws + (size_t)ctile * 16 * 8192;

    f32x4_t acc[4][4];
#pragma unroll
    for (int m = 0; m < 4; ++m)
#pragma unroll
      for (int n = 0; n < 4; ++n) acc[m][n] = (f32x4_t){0.f, 0.f, 0.f, 0.f};

    for (int st = 0; st < 16; ++st) {
      const unsigned char* Asrc = Ach + (size_t)st * 8192;
      const unsigned char* Bsrc = Bch + (size_t)st * 8192;
#pragma unroll
      for (int i = 0; i < 4; ++i) {
        const int j = wave * 4 + i;  // 16 x 1KB units: A 0-7, B 8-15
        const unsigned char* sp = (j < 8) ? (Asrc + (size_t)j * 1024 + lane * 16)
                                          : (Bsrc + (size_t)(j - 8) * 1024 + lane * 16);
        __builtin_amdgcn_global_load_lds(
            (const __attribute__((address_space(1))) void*)sp,
            (__attribute__((address_space(3))) void*)(smem + j * 1024), 16, 0, 0);
      }
      __syncthreads();  // compiler drains vmcnt before barrier (m97 pattern)

      bf16x8_t ah[4], bh[4];
#pragma unroll
      for (int m = 0; m < 4; ++m) {
        const int r = wr * 64 + m * 16 + lr;
        ah[m] = *(const bf16x8_t*)(smem + swz_off(r, kg));
      }
#pragma unroll
      for (int n = 0; n < 4; ++n) {
        const int r = wc * 64 + n * 16 + lr;
        bh[n] = *(const bf16x8_t*)(smem + 8192 + swz_off(r, kg));
      }
#pragma unroll
      for (int m = 0; m < 4; ++m)
#pragma unroll
        for (int n = 0; n < 4; ++n)
          acc[m][n] = __builtin_amdgcn_mfma_f32_16x16x32_bf16(ah[m], bh[n], acc[m][n], 0, 0, 0);
      __syncthreads();  // reads done before next stage overwrites
    }

    // epilogue: 64-col halves through LDS, per-row top-4 for THIS ctile
    float v4[4]; int id4[4];
#pragma unroll
    for (int s = 0; s < 4; ++s) { v4[s] = -3e38f; id4[s] = 0; }
#pragma unroll
    for (int ph = 0; ph < 2; ++ph) {
      if (wc == ph) {
#pragma unroll
        for (int m = 0; m < 4; ++m)
#pragma unroll
          for (int n = 0; n < 4; ++n)
#pragma unroll
            for (int j = 0; j < 4; ++j)
              slog[(wr * 64 + m * 16 + kg * 4 + j) * LSTR + n * 16 + lr] = acc[m][n][j];
      }
      __syncthreads();
      if (tid < 128) {
        const int gbase = code0 + ph * 64;
        for (int c = 0; c < 64; ++c) {
          float v = slog[tid * LSTR + c];
          if (v > v4[3]) {
            v4[3] = v; id4[3] = gbase + c;
#pragma unroll
            for (int s = 3; s > 0; --s)
              if (v4[s] > v4[s - 1]) {
                float tv = v4[s]; v4[s] = v4[s - 1]; v4[s - 1] = tv;
                int ti = id4[s]; id4[s] = id4[s - 1]; id4[s - 1] = ti;
              }
          }
        }
      }
      __syncthreads();
    }
    if (tid < 128) {
      float2* p = top4 + ((size_t)(rb * 128 + tid) * 32 + ctile) * 4;
#pragma unroll
      for (int s = 0; s < 4; ++s)
        p[s] = make_float2(v4[s], __builtin_bit_cast(float, id4[s]));
    }
  }
}

// ---------------- resolve: mask probe + merge 32x top-4, classify rows ----------------
__global__ void resolve_kernel(const uint4* __restrict__ mk, const float2* __restrict__ top4,
                               int* __restrict__ idxf, int* __restrict__ cands,
                               int* __restrict__ full, unsigned* __restrict__ flags) {
  if (blockIdx.x == 0) {
    unsigned f = 0;
    for (int i = threadIdx.x; i < 1024; i += 256) {
      uint4 v = mk[i];
      f |= hz(v.x) | hz(v.y) | hz(v.z) | hz(v.w);
    }
    if (f) atomicOr(&flags[0], 1u);  // zero byte found -> int32 mask layout
  }
  const int row = blockIdx.x * 256 + threadIdx.x;
  if (row >= NROWS) return;
  const float2* e = top4 + (size_t)row * 128;  // 32 groups x 4 slots
  float V1 = -3e38f; int I1 = 0;
  for (int j = 0; j < 128; ++j) {
    float v = e[j].x;
    if (v > V1) { V1 = v; I1 = __builtin_bit_cast(int, e[j].y); }
  }
  const float T = V1 - 2.0f * DELTA;
  bool fullscan = false;
#pragma unroll
  for (int g = 0; g < 32; ++g)
    if (e[g * 4 + 3].x >= T) fullscan = true;  // group top-4 may have truncated candidates
  int cnt = 0; int cid[MAXC];
  for (int j = 0; j < 128; ++j) {
    if (e[j].x >= T) { if (cnt < MAXC) cid[cnt] = __builtin_bit_cast(int, e[j].y); ++cnt; }
  }
  if (cnt > MAXC) fullscan = true;
  idxf[row] = I1;  // provably correct when cnt==1
  if (fullscan) {
    unsigned s = atomicAdd(&flags[2], 1u);
    if (s < FULL_CAP) full[s] = row;
  } else if (cnt >= 2) {
    unsigned s = atomicAdd(&flags[1], 1u);
    int* o = cands + (size_t)s * 20;
    o[0] = row; o[1] = cnt;
#pragma unroll
    for (int c2 = 0; c2 < MAXC; ++c2) o[2 + c2] = (c2 < cnt) ? cid[c2] : 0;
  }
}

// ---------------- f64 candidate rescore: one wave per row ----------------
__global__ void rescore_cand_kernel(const float* __restrict__ z, const float* __restrict__ cb,
                                    const int* __restrict__ cands, const unsigned* __restrict__ flags,
                                    int* __restrict__ idxf) {
  const int lane = threadIdx.x & 63;
  const int gw = (blockIdx.x * 256 + threadIdx.x) >> 6;
  const unsigned n = flags[1];
  for (unsigned it = gw; it < n; it += 512) {
    const int* en = cands + (size_t)it * 20;
    const int row = en[0], cnt = en[1];
    const float* zr = z + (size_t)row * DIM + lane * 8;
    double zv[8];
#pragma unroll
    for (int j = 0; j < 8; ++j) zv[j] = (double)zr[j];
    double bs = -1e300; int bi = 1 << 30;
    for (int c = 0; c < cnt; ++c) {
      const int k = en[2 + c];
      const float* ck = cb + (size_t)k * DIM + lane * 8;
      double da = 0, nb = 0;
#pragma unroll
      for (int j = 0; j < 8; ++j) { double cv = ck[j]; da += zv[j] * cv; nb += cv * cv; }
#pragma unroll
      for (int off = 1; off < 64; off <<= 1) {
        da += __shfl_xor(da, off); nb += __shfl_xor(nb, off);
      }
      double sc = da / sqrt(nb);  // z-norm omitted: row-constant scale, argmax-invariant
      if (sc > bs || (sc == bs && k < bi)) { bs = sc; bi = k; }
    }
    if (lane == 0) idxf[row] = bi;
  }
}

// ---------------- f64 full-row referee stage 1: (row, 128-code chunk) work units ----------------
// 32 chunks/row across the grid; each code = 2 threads (256 dims each), block-reduce chunk best.
__global__ void rescore_full_part(const float* __restrict__ z, const float* __restrict__ cb,
                                  const int* __restrict__ full, const unsigned* __restrict__ flags,
                                  double2* __restrict__ fpart) {
  __shared__ float zrow[DIM];
  __shared__ double sv[128];
  __shared__ int si[128];
  const int t = threadIdx.x;
  unsigned n = flags[2];
  if (n > FULL_CAP) n = FULL_CAP;
  for (unsigned u = blockIdx.x; u < n * 32; u += gridDim.x) {
    const unsigned it = u >> 5, chunk = u & 31;
    const int row = full[it];
    __syncthreads();  // protect zrow from previous iteration's readers
    for (int j = t; j < DIM; j += 256) zrow[j] = z[(size_t)row * DIM + j];
    __syncthreads();
    const int k = (int)chunk * 128 + (t >> 1);
    const int half = t & 1;
    const float* ck = cb + (size_t)k * DIM + half * 256;
    const float* zp = zrow + half * 256;
    double d = 0, nn = 0;
    for (int j = 0; j < 256; j += 4) {
      f32x4_t cv = *(const f32x4_t*)(ck + j);
      f32x4_t zv = *(const f32x4_t*)(zp + j);
#pragma unroll
      for (int e = 0; e < 4; ++e) {
        const double c = (double)cv[e];
        d += (double)zv[e] * c; nn += c * c;
      }
    }
    d += __shfl_xor(d, 1); nn += __shfl_xor(nn, 1);
    if (half == 0) { sv[t >> 1] = d / sqrt(nn); si[t >> 1] = k; }
    __syncthreads();
    for (int off = 64; off; off >>= 1) {
      if (t < off) {
        if (sv[t + off] > sv[t] || (sv[t + off] == sv[t] && si[t + off] < si[t])) {
          sv[t] = sv[t + off]; si[t] = si[t + off];
        }
      }
      __syncthreads();
    }
    if (t == 0) fpart[u] = make_double2(sv[0], (double)si[0]);
  }
}

// ---------------- f64 full-row referee stage 2: merge 32 chunk-bests per row ----------------
__global__ void rescore_full_merge(const double2* __restrict__ fpart, const int* __restrict__ full,
                                   const unsigned* __restrict__ flags, int* __restrict__ idxf) {
  const int wv = threadIdx.x >> 6, lane = threadIdx.x & 63;
  unsigned n = flags[2];
  if (n > FULL_CAP) n = FULL_CAP;
  for (unsigned it = blockIdx.x * 4 + wv; it < n; it += gridDim.x * 4) {
    double bs = -1e300; int bi = 1 << 30;
    if (lane < 32) {
      double2 e = fpart[(size_t)it * 32 + lane];
      bs = e.x; bi = (int)e.y;
    }
#pragma unroll
    for (int off = 16; off; off >>= 1) {
      double os = __shfl_down(bs, off);
      int oi = __shfl_down(bi, off);
      if (os > bs || (os == bs && oi < bi)) { bs = os; bi = oi; }
    }
    if (lane == 0) idxf[full[it]] = bi;
  }
}

// ---------------- gather + straight-through + partial losses ----------------
__global__ void outputs_kernel(const float* __restrict__ z, const float* __restrict__ cb,
                               const unsigned char* __restrict__ mask8, const int* __restrict__ mask32,
                               const unsigned* __restrict__ flags, const int* __restrict__ idxf,
                               float* __restrict__ out, unsigned* __restrict__ counts,
                               double* __restrict__ cpart) {
  __shared__ double wsum[4];
  const int wv = threadIdx.x >> 6, lane = threadIdx.x & 63;
  const int row = blockIdx.x * 4 + wv;
  int idx = idxf[row];
  idx = (idx < 0) ? 0 : ((idx > NCODES - 1) ? NCODES - 1 : idx);  // defensive clamp
  const int mi = flags[0] ? (mask32[row] != 0) : (mask8[row] != 0);
  const float mf = mi ? 1.0f : 0.0f;
  const float* zr = z + (size_t)row * DIM;
  const float* cr = cb + (size_t)idx * DIM;
  double cs = 0.0;
#pragma unroll
  for (int h = 0; h < 2; ++h) {
    const int j = h * 256 + lane * 4;
    f32x4_t c  = *(const f32x4_t*)(cr + j);
    f32x4_t ze = *(const f32x4_t*)(zr + j);
    f32x4_t zq, zs;
#pragma unroll
    for (int e = 0; e < 4; ++e) {
      float qv = c[e] * mf;
      float d = qv - ze[e];
      zq[e] = qv;
      zs[e] = ze[e] + d;
      cs += (double)(d * d) * mf;
    }
    *(f32x4_t*)(out + OUT_ZQ   + (size_t)row * DIM + j) = zq;
    *(f32x4_t*)(out + OUT_ZQST + (size_t)row * DIM + j) = zs;
  }
#pragma unroll
  for (int off = 32; off; off >>= 1) cs += __shfl_down(cs, off);
  if (lane == 0) {
    wsum[wv] = cs;
    out[OUT_IDX + row] = (float)idx;
    if (mi) atomicAdd(&counts[idx], 1u);
  }
  __syncthreads();
  if (threadIdx.x == 0) cpart[blockIdx.x] = wsum[0] + wsum[1] + wsum[2] + wsum[3];
}

// ---------------- scalars ----------------
__global__ void finalize_kernel(const double* __restrict__ cpart, const unsigned* __restrict__ counts,
                                float* __restrict__ out) {
  __shared__ double sd[256];
  const int t = threadIdx.x;
  double s = 0;
  for (int i = t; i < 4096; i += 256) s += cpart[i];
  sd[t] = s; __syncthreads();
  for (int off = 128; off; off >>= 1) { if (t < off) sd[t] += sd[t + off]; __syncthreads(); }
  const double commit_sum = sd[0];
  __syncthreads();
  double c = 0;
  for (int i = t; i < 4096; i += 256) c += (double)counts[i];
  sd[t] = c; __syncthreads();
  for (int off = 128; off; off >>= 1) { if (t < off) sd[t] += sd[t + off]; __syncthreads(); }
  const double totc = sd[0];
  __syncthreads();
  const double denom = totc + 1e-5;
  double ent = 0;
  for (int i = t; i < 4096; i += 256) {
    double p = (double)counts[i] / denom;
    ent -= p * log(p + 1e-5);
  }
  sd[t] = ent; __syncthreads();
  for (int off = 128; off; off >>= 1) { if (t < off) sd[t] += sd[t + off]; __syncthreads(); }
  if (t == 0) {
    const double valid = fmax(totc, 1.0);
    const double commitment = commit_sum / valid;
    out[OUT_VQ]     = (float)(0.25 * commitment);
    out[OUT_COMMIT] = (float)commitment;
    out[OUT_PERP]   = (float)exp(sd[0]);
  }
}

extern "C" void kernel_launch(void* const* d_in, const int* in_sizes, int n_in,
                              void* d_out, int out_size, void* d_ws, size_t ws_size,
                              hipStream_t stream) {
  const float* z  = (const float*)d_in[0];
  const void*  mk = d_in[1];
  const float* cb = (const float*)d_in[2];
  float* out = (float*)d_out;
  char* ws = (char*)d_ws;

  unsigned char* Aws    = (unsigned char*)(ws + WS_A);
  unsigned char* Bws    = (unsigned char*)(ws + WS_B);
  float2*        top4   = (float2*)(ws + WS_TOP4);
  unsigned*      counts = (unsigned*)(ws + WS_COUNTS);
  unsigned*      flags  = (unsigned*)(ws + WS_FLAGS);
  int*           idxf   = (int*)(ws + WS_IDX);
  int*           cands  = (int*)(ws + WS_CANDS);
  int*           full   = (int*)(ws + WS_FULL);
  double*        cpart  = (double*)(ws + WS_CPART);
  double2*       fpart  = (double2*)(ws + WS_FPART);

  prep_kernel<<<(NROWS + NCODES) / 4, 256, 0, stream>>>(z, cb, Aws, Bws, counts);
  gemm_p1_kernel<<<1024, 256, 0, stream>>>(Aws, Bws, top4);
  resolve_kernel<<<NROWS / 256, 256, 0, stream>>>((const uint4*)mk, top4, idxf, cands, full, flags);
  rescore_cand_kernel<<<128, 256, 0, stream>>>(z, cb, cands, flags, idxf);
  rescore_full_part<<<1024, 256, 0, stream>>>(z, cb, full, flags, fpart);
  rescore_full_merge<<<32, 256, 0, stream>>>(fpart, full, flags, idxf);
  outputs_kernel<<<NROWS / 4, 256, 0, stream>>>(z, cb, (const unsigned char*)mk, (const int*)mk,
                                                flags, idxf, out, counts, cpart);
  finalize_kernel<<<1, 256, 0, stream>>>(cpart, counts, out);
}